// Round 1
// baseline (43.947 us; speedup 1.0000x reference)
//
#include <hip/hip_runtime.h>

#define NA 3
#define NCLS 3
#define NB 12
#define BATCH 128

struct BoxMeta { int gi, gj, flags, cls; float tw, th; };
// flags: bits 0..2 = clear mask per anchor (already ANDed with valid)
//        bits 4..6 = obj mask (valid ? 1<<best : 0)

__global__ void prep_boxes(const float* __restrict__ boxes,
                           const int* __restrict__ labels,
                           BoxMeta* __restrict__ meta) {
    int t = blockIdx.x * blockDim.x + threadIdx.x;
    if (t >= 3 * BATCH * NB) return;
    int s = t / (BATCH * NB);
    int r = t % (BATCH * NB);
    int b = r / NB, n = r % NB;

    const float AW[3][3] = {{3.625f, 4.875f, 11.65625f},
                            {1.875f, 3.875f, 3.6875f},
                            {1.25f,  2.0f,   4.125f}};
    const float AH[3][3] = {{2.8125f, 6.1875f, 10.1875f},
                            {3.8125f, 2.8125f, 7.4375f},
                            {1.625f,  3.75f,   2.875f}};
    const int GS[3] = {19, 38, 76};
    int G = GS[s];

    float4 bx = ((const float4*)boxes)[b * NB + n];
    int lab = labels[b * NB + n];
    bool valid = lab < NCLS;

    float tbx = bx.x * (float)G, tby = bx.y * (float)G;
    float bw  = bx.z * (float)G, bh  = bx.w * (float)G;
    int gi = min(max((int)tbx, 0), G - 1);
    int gj = min(max((int)tby, 0), G - 1);

    float iou[3]; int best = 0; float bi = -1.0f;
    for (int a = 0; a < 3; a++) {
        float aw = AW[s][a], ah = AH[s][a];
        float inter = fminf(aw, bw) * fminf(ah, bh);
        float uni = aw * ah + 1e-16f + bw * bh - inter;
        iou[a] = inter / uni;
        if (iou[a] > bi) { bi = iou[a]; best = a; }
    }
    int flags = 0;
    if (valid) {
        for (int a = 0; a < 3; a++)
            if (iou[a] > 0.5f || a == best) flags |= (1 << a);
        flags |= (1 << (4 + best));
    }
    BoxMeta m;
    m.gi = gi; m.gj = gj; m.flags = flags;
    m.cls = min(max(lab, 0), NCLS - 1);
    m.tw = valid ? logf(bw / AW[s][best] + 1e-16f) : 0.0f;
    m.th = valid ? logf(bh / AH[s][best] + 1e-16f) : 0.0f;
    meta[t] = m;
}

__device__ __forceinline__ float safelog(float x) {
    return fmaxf(logf(x), -100.0f);
}

template <int G, int S, int ITER>
__launch_bounds__(256)
__global__ void scale_loss(const float* __restrict__ out,
                           const BoxMeta* __restrict__ meta,
                           float* __restrict__ partials) {
    constexpr int CELLS = NA * G * G;
    const int b = blockIdx.y;
    const int tid = threadIdx.x;

    __shared__ int sbox[NB * 6];
    __shared__ float red[256];
    if (tid < NB * 6)
        sbox[tid] = ((const int*)(meta + (S * BATCH + b) * NB))[tid];
    __syncthreads();

    constexpr float AWs[3][3] = {{3.625f, 4.875f, 11.65625f},
                                 {1.875f, 3.875f, 3.6875f},
                                 {1.25f,  2.0f,   4.125f}};
    constexpr float AHs[3][3] = {{2.8125f, 6.1875f, 10.1875f},
                                 {3.8125f, 2.8125f, 7.4375f},
                                 {1.625f,  3.75f,   2.875f}};

    const float* outb = out + (size_t)b * CELLS * 8;
    float acc = 0.0f;
    const int base = blockIdx.x * (256 * ITER);

    for (int k = 0; k < ITER; k++) {
        int c = base + k * 256 + tid;
        if (c < CELLS) {
            int a   = c / (G * G);          // compile-time G -> magic mul
            int rem = c - a * (G * G);
            int gj  = rem / G;
            int gi  = rem - gj * G;

            const float4* p = (const float4*)(outb + (size_t)c * 8);
            float4 q0 = p[0];
            float4 q1 = p[1];

            float keepv = 1.0f;
            bool obj = false;
            float tw = 0.0f, th = 0.0f;
            int cls = 0;
#pragma unroll
            for (int n = 0; n < NB; n++) {
                if (sbox[n * 6 + 0] == gi && sbox[n * 6 + 1] == gj) {
                    int fl = sbox[n * 6 + 2];
                    if ((fl >> a) & 1) keepv = 0.0f;
                    if ((fl >> (4 + a)) & 1) {
                        obj = true;
                        cls = sbox[n * 6 + 3];
                        tw  = __int_as_float(sbox[n * 6 + 4]);
                        th  = __int_as_float(sbox[n * 6 + 5]);
                    }
                }
            }

            float conf = q1.x;
            // noobj: 0.5 * noobj * bce(conf, 0) ; noobj==0 wherever obj==1
            float loss = -0.5f * keepv * safelog(1.0f - conf);

            if (obj) {
                float aw = AWs[S][a], ah = AHs[S][a];
                float px = q0.x - floorf(q0.x);
                float py = q0.y - floorf(q0.y);
                float pw = logf(q0.z / aw + 1e-16f);
                float ph = logf(q0.w / ah + 1e-16f);
                float dw = pw - tw, dh = ph - th;
                loss += px * px + py * py + dw * dw + dh * dh;
                loss += -5.0f * safelog(conf);          // OBJ_SCALE * bce(conf, 1)
                float c0 = q1.y, c1 = q1.z, c2 = q1.w;
                loss -= (cls == 0) ? safelog(c0) : safelog(1.0f - c0);
                loss -= (cls == 1) ? safelog(c1) : safelog(1.0f - c1);
                loss -= (cls == 2) ? safelog(c2) : safelog(1.0f - c2);
            }
            acc += loss;
        }
    }

    red[tid] = acc;
    __syncthreads();
    for (int s = 128; s > 0; s >>= 1) {
        if (tid < s) red[tid] += red[tid + s];
        __syncthreads();
    }
    if (tid == 0)
        partials[blockIdx.y * gridDim.x + blockIdx.x] = red[0];
}

__global__ void final_reduce(const float* __restrict__ partials, int n,
                             float* __restrict__ out) {
    __shared__ float red[256];
    float acc = 0.0f;
    for (int i = threadIdx.x; i < n; i += 256) acc += partials[i];
    red[threadIdx.x] = acc;
    __syncthreads();
    for (int s = 128; s > 0; s >>= 1) {
        if (threadIdx.x < s) red[threadIdx.x] += red[threadIdx.x + s];
        __syncthreads();
    }
    if (threadIdx.x == 0) out[0] = red[0] * (1.0f / (float)BATCH);
}

extern "C" void kernel_launch(void* const* d_in, const int* in_sizes, int n_in,
                              void* d_out, int out_size, void* d_ws, size_t ws_size,
                              hipStream_t stream) {
    const float* oL    = (const float*)d_in[0];
    const float* oM    = (const float*)d_in[1];
    const float* oS    = (const float*)d_in[2];
    const float* boxes = (const float*)d_in[3];
    const int*   labels= (const int*)d_in[4];

    BoxMeta* meta   = (BoxMeta*)d_ws;
    float* partials = (float*)((char*)d_ws + 3 * BATCH * NB * sizeof(BoxMeta)); // 110592 B

    prep_boxes<<<(3 * BATCH * NB + 255) / 256, 256, 0, stream>>>(boxes, labels, meta);

    // G=19: 1083 cells, 1 block/b ; G=38: 4332 cells, 4 blocks/b ; G=76: 17328 cells, 9 blocks/b
    scale_loss<19, 0, 5><<<dim3(1, BATCH), 256, 0, stream>>>(oL, meta, partials + 0);
    scale_loss<38, 1, 5><<<dim3(4, BATCH), 256, 0, stream>>>(oM, meta, partials + 128);
    scale_loss<76, 2, 8><<<dim3(9, BATCH), 256, 0, stream>>>(oS, meta, partials + 640);

    final_reduce<<<1, 256, 0, stream>>>(partials, 128 + 512 + 1152, (float*)d_out);
}

// Round 2
// 25.831 us; speedup vs baseline: 1.7013x; 1.7013x over previous
//
#include <hip/hip_runtime.h>

#define NA 3
#define NCLS 3
#define NB 12
#define BATCH 128

__device__ __forceinline__ float safelog(float x) {
    return fmaxf(logf(x), -100.0f);
}

// Anchors per scale (already divided by stride)
__device__ __constant__ float AWc[3][3] = {{3.625f, 4.875f, 11.65625f},
                                           {1.875f, 3.875f, 3.6875f},
                                           {1.25f,  2.0f,   4.125f}};
__device__ __constant__ float AHc[3][3] = {{2.8125f, 6.1875f, 10.1875f},
                                           {3.8125f, 2.8125f, 7.4375f},
                                           {1.625f,  3.75f,   2.875f}};

// sbox layout per box: gi, gj, flags, cls, tw(bits), th(bits)
// flags: bits 0..2 = clear mask per anchor (ANDed with valid)
//        bits 4..6 = obj mask (valid ? 1<<best : 0)

template <int G, int S, int ITER>
__device__ __forceinline__ void scale_body(int b, int chunk,
                                           const float* __restrict__ outp,
                                           const float* __restrict__ boxes,
                                           const int* __restrict__ labels,
                                           int* sbox, float* red,
                                           float* __restrict__ partials, int pidx) {
    constexpr int CELLS = NA * G * G;
    const int tid = threadIdx.x;

    // ---- in-block box meta (threads 0..11) ----
    if (tid < NB) {
        float4 bx = ((const float4*)boxes)[b * NB + tid];
        int lab = labels[b * NB + tid];
        bool valid = lab < NCLS;

        float bw = bx.z * (float)G, bh = bx.w * (float)G;
        int gi = min(max((int)(bx.x * (float)G), 0), G - 1);
        int gj = min(max((int)(bx.y * (float)G), 0), G - 1);

        float iou[3]; int best = 0; float bi = -1.0f;
#pragma unroll
        for (int a = 0; a < 3; a++) {
            float aw = AWc[S][a], ah = AHc[S][a];
            float inter = fminf(aw, bw) * fminf(ah, bh);
            float uni = aw * ah + 1e-16f + bw * bh - inter;
            iou[a] = inter / uni;
            if (iou[a] > bi) { bi = iou[a]; best = a; }
        }
        int flags = 0;
        if (valid) {
#pragma unroll
            for (int a = 0; a < 3; a++)
                if (iou[a] > 0.5f || a == best) flags |= (1 << a);
            flags |= (1 << (4 + best));
        }
        sbox[tid * 6 + 0] = gi;
        sbox[tid * 6 + 1] = gj;
        sbox[tid * 6 + 2] = flags;
        sbox[tid * 6 + 3] = min(max(lab, 0), NCLS - 1);
        sbox[tid * 6 + 4] = __float_as_int(valid ? logf(bw / AWc[S][best] + 1e-16f) : 0.0f);
        sbox[tid * 6 + 5] = __float_as_int(valid ? logf(bh / AHc[S][best] + 1e-16f) : 0.0f);
    }
    __syncthreads();

    const float* outb = outp + (size_t)b * CELLS * 8;
    float acc = 0.0f;
    const int base = chunk * (256 * ITER);

#pragma unroll
    for (int k = 0; k < ITER; k++) {
        int c = base + k * 256 + tid;
        if (c < CELLS) {
            int a   = c / (G * G);
            int rem = c - a * (G * G);
            int gj  = rem / G;
            int gi  = rem - gj * G;

            const float4* p = (const float4*)(outb + (size_t)c * 8);
            float4 q0 = p[0];
            float4 q1 = p[1];

            float keepv = 1.0f;
            bool obj = false;
            float tw = 0.0f, th = 0.0f;
            int cls = 0;
#pragma unroll
            for (int n = 0; n < NB; n++) {
                if (sbox[n * 6 + 0] == gi && sbox[n * 6 + 1] == gj) {
                    int fl = sbox[n * 6 + 2];
                    if ((fl >> a) & 1) keepv = 0.0f;
                    if ((fl >> (4 + a)) & 1) {
                        obj = true;
                        cls = sbox[n * 6 + 3];
                        tw  = __int_as_float(sbox[n * 6 + 4]);
                        th  = __int_as_float(sbox[n * 6 + 5]);
                    }
                }
            }

            float conf = q1.x;
            float loss = -0.5f * keepv * safelog(1.0f - conf);  // NOOBJ_SCALE * bce(conf,0)

            if (obj) {
                float aw = AWc[S][a], ah = AHc[S][a];
                float px = q0.x - floorf(q0.x);
                float py = q0.y - floorf(q0.y);
                float pw = logf(q0.z / aw + 1e-16f);
                float ph = logf(q0.w / ah + 1e-16f);
                float dw = pw - tw, dh = ph - th;
                loss += px * px + py * py + dw * dw + dh * dh;
                loss += -5.0f * safelog(conf);                  // OBJ_SCALE * bce(conf,1)
                float c0 = q1.y, c1 = q1.z, c2 = q1.w;
                loss -= (cls == 0) ? safelog(c0) : safelog(1.0f - c0);
                loss -= (cls == 1) ? safelog(c1) : safelog(1.0f - c1);
                loss -= (cls == 2) ? safelog(c2) : safelog(1.0f - c2);
            }
            acc += loss;
        }
    }

    red[tid] = acc;
    __syncthreads();
    for (int s = 128; s > 0; s >>= 1) {
        if (tid < s) red[tid] += red[tid + s];
        __syncthreads();
    }
    if (tid == 0) partials[pidx] = red[0];
}

__launch_bounds__(256)
__global__ void fused_loss(const float* __restrict__ oL,
                           const float* __restrict__ oM,
                           const float* __restrict__ oS,
                           const float* __restrict__ boxes,
                           const int* __restrict__ labels,
                           float* __restrict__ partials) {
    __shared__ int sbox[NB * 6];
    __shared__ float red[256];
    int idx = blockIdx.x;
    if (idx < 128) {
        scale_body<19, 0, 5>(idx, 0, oL, boxes, labels, sbox, red, partials, idx);
    } else if (idx < 640) {
        int r = idx - 128;
        scale_body<38, 1, 5>(r >> 2, r & 3, oM, boxes, labels, sbox, red, partials, idx);
    } else {
        int r = idx - 640;
        scale_body<76, 2, 8>(r / 9, r % 9, oS, boxes, labels, sbox, red, partials, idx);
    }
}

__global__ void final_reduce(const float* __restrict__ partials, int n,
                             float* __restrict__ out) {
    __shared__ float red[256];
    float acc = 0.0f;
    for (int i = threadIdx.x; i < n; i += 256) acc += partials[i];
    red[threadIdx.x] = acc;
    __syncthreads();
    for (int s = 128; s > 0; s >>= 1) {
        if (threadIdx.x < s) red[threadIdx.x] += red[threadIdx.x + s];
        __syncthreads();
    }
    if (threadIdx.x == 0) out[0] = red[0] * (1.0f / (float)BATCH);
}

extern "C" void kernel_launch(void* const* d_in, const int* in_sizes, int n_in,
                              void* d_out, int out_size, void* d_ws, size_t ws_size,
                              hipStream_t stream) {
    const float* oL     = (const float*)d_in[0];
    const float* oM     = (const float*)d_in[1];
    const float* oS     = (const float*)d_in[2];
    const float* boxes  = (const float*)d_in[3];
    const int*   labels = (const int*)d_in[4];

    float* partials = (float*)d_ws;  // 1792 floats

    fused_loss<<<1792, 256, 0, stream>>>(oL, oM, oS, boxes, labels, partials);
    final_reduce<<<1, 256, 0, stream>>>(partials, 1792, (float*)d_out);
}